// Round 5
// baseline (282.756 us; speedup 1.0000x reference)
//
#include <hip/hip_runtime.h>

typedef unsigned short ushort_t;
typedef __attribute__((ext_vector_type(8))) short bf16x8;
typedef __attribute__((ext_vector_type(4))) float f32x4;
typedef __attribute__((ext_vector_type(16))) float f32x16;

__device__ __forceinline__ unsigned short f2bf(float f) {
  union { float f; unsigned int u; } v; v.f = f;
  unsigned int r = v.u + 0x7FFFu + ((v.u >> 16) & 1u);
  return (unsigned short)(r >> 16);
}

__device__ __forceinline__ void gl_lds16(const void* gsrc, void* ldst) {
  __builtin_amdgcn_global_load_lds(
      (const __attribute__((address_space(1))) void*)gsrc,
      (__attribute__((address_space(3))) void*)ldst, 16, 0, 0);
}

__device__ __forceinline__ f32x16 zero16() {
  f32x16 z;
  #pragma unroll
  for (int i = 0; i < 16; i++) z[i] = 0.f;
  return z;
}

__device__ __forceinline__ int frag_idx(int oc, int ci) {
  return (((oc>>4)*8 + (ci>>5))<<9) + ((((ci>>3)&3)*16 + (oc&15))<<3) + (ci&7);
}

// ---------------------------------------------------------------------------
// K1: fragment-major bf16 weight bank Wf[640][256] (Q=wq, K=wk, V=w128@wv)
//     + bias_all[640].  Blocks 0..511: copy/cast QK.  Blocks 512..543: V-fold,
//     4 oc per block (wv read once per block -> 8 MB total, was 32 MB).
// ---------------------------------------------------------------------------
__global__ __launch_bounds__(256) void k1_weights(
    const float* __restrict__ wq, const float* __restrict__ bq,
    const float* __restrict__ wk, const float* __restrict__ bk,
    const float* __restrict__ wv, const float* __restrict__ bv,
    const float* __restrict__ w128,
    ushort_t* __restrict__ Wf, float* __restrict__ bias_all)
{
  const int ci = threadIdx.x;
  if (blockIdx.x < 512) {
    const int oc = blockIdx.x;
    const float v = (oc < 256) ? wq[oc*256 + ci] : wk[(oc-256)*256 + ci];
    Wf[frag_idx(oc, ci)] = f2bf(v);
    if (ci == 0) bias_all[oc] = (oc < 256) ? bq[oc] : bk[oc-256];
  } else {
    const int og = (blockIdx.x - 512) * 4;   // V out-channel group (0..124)
    float a0 = 0.f, a1 = 0.f, a2 = 0.f, a3 = 0.f;
    for (int co = 0; co < 256; co++) {
      const float wvv = wv[co*256 + ci];
      a0 += w128[(og+0)*256 + co] * wvv;
      a1 += w128[(og+1)*256 + co] * wvv;
      a2 += w128[(og+2)*256 + co] * wvv;
      a3 += w128[(og+3)*256 + co] * wvv;
    }
    Wf[frag_idx(512+og+0, ci)] = f2bf(a0);
    Wf[frag_idx(512+og+1, ci)] = f2bf(a1);
    Wf[frag_idx(512+og+2, ci)] = f2bf(a2);
    Wf[frag_idx(512+og+3, ci)] = f2bf(a3);
    if (ci < 4) {
      float s = 0.f;
      for (int co = 0; co < 256; co++) s += w128[(og+ci)*256 + co] * bv[co];
      bias_all[512 + og + ci] = s;
    }
  }
}

// ---------------------------------------------------------------------------
// K2: MFMA feature GEMM (16x16x32 internally). Grid 256 blocks = 64-px tiles.
//   ot 0..3 -> Qf, 4..7 -> Kf emitted in 32x32x16 A/B-frag layout:
//     frag[lane][j] = X[pg*32 + (lane&31)][kb*16 + (lane>>5)*8 + j]
//   ot 8..9 -> V fp32 [src*8+b][oc][hw]
// ---------------------------------------------------------------------------
__global__ __launch_bounds__(256) void k2_features(
    const float* __restrict__ x4, const float* __restrict__ x3,
    const ushort_t* __restrict__ Wf, const float* __restrict__ bias_all,
    ushort_t* __restrict__ Qf, ushort_t* __restrict__ Kf, float* __restrict__ V)
{
  __shared__ ushort_t Af[32*512];      // 32 KB
  __shared__ ushort_t Wl[2][32*512];   // 2 x 32 KB
  __shared__ ushort_t Lt[64*72];       // repack buffer

  const int tid = threadIdx.x;
  const int w = tid >> 6, lane = tid & 63;
  const int mrow = lane & 15, quad = lane >> 4;
  const int ln31 = lane & 31, half = lane >> 5;

  const int px0 = blockIdx.x * 64;
  const int src = px0 >> 13, b = (px0 >> 10) & 7, hw0 = px0 & 1023;
  const float* xp = (src ? x3 : x4) + (size_t)b*262144;

  for (int kb = 0; kb < 8; kb++)
    gl_lds16(Wf + ((size_t)((0*4 + w)*8 + kb)<<9) + lane*8, &Wl[0][(w*8+kb)*512]);

  {
    const int hw = hw0 + w*16 + mrow;
    for (int kb = 0; kb < 8; kb++) {
      const int ch0 = kb*32 + quad*8;
      bf16x8 pk;
      #pragma unroll
      for (int j = 0; j < 8; j++)
        ((ushort_t*)&pk)[j] = f2bf(xp[(size_t)(ch0 + j)*1024 + hw]);
      *(bf16x8*)&Af[(w*8 + kb)*512 + lane*8] = pk;
    }
  }
  __syncthreads();

  for (int ot = 0; ot < 10; ot++) {
    const int nbuf = (ot+1) & 1, cbuf = ot & 1;
    if (ot < 9)
      for (int kb = 0; kb < 8; kb++)
        gl_lds16(Wf + ((size_t)(((ot+1)*4 + w)*8 + kb)<<9) + lane*8,
                 &Wl[nbuf][(w*8+kb)*512]);
    asm volatile("s_waitcnt vmcnt(8)" ::: "memory");

    f32x4 acc[4];
    #pragma unroll
    for (int lg = 0; lg < 4; lg++) acc[lg] = (f32x4){0.f,0.f,0.f,0.f};
    #pragma unroll
    for (int kb = 0; kb < 8; kb++) {
      const bf16x8 a = *(const bf16x8*)&Wl[cbuf][(w*8 + kb)*512 + lane*8];
      #pragma unroll
      for (int lg = 0; lg < 4; lg++) {
        const bf16x8 bx = *(const bf16x8*)&Af[(lg*8 + kb)*512 + lane*8];
        acc[lg] = __builtin_amdgcn_mfma_f32_16x16x32_bf16(a, bx, acc[lg], 0, 0, 0);
      }
    }
    const int ocl = w*16 + quad*4;
    const float4 bias4 = *(const float4*)&bias_all[ot*64 + ocl];

    if (ot < 8) {
      __syncthreads();
      #pragma unroll
      for (int lg = 0; lg < 4; lg++) {
        const int px = lg*16 + mrow;
        ushort4 pk;
        pk.x = f2bf(acc[lg][0] + bias4.x);
        pk.y = f2bf(acc[lg][1] + bias4.y);
        pk.z = f2bf(acc[lg][2] + bias4.z);
        pk.w = f2bf(acc[lg][3] + bias4.w);
        *(ushort4*)&Lt[px*72 + ocl] = pk;
      }
      __syncthreads();
      // emit 32x32x16 A/B fragments: 8 chunks (pg 0..1 x kbl 0..3), 2 per wave
      ushort_t* dst = (ot < 4) ? Qf : Kf;
      const int kbase = (ot & 3)*4;
      #pragma unroll
      for (int e = 0; e < 2; e++) {
        const int cc = w*2 + e;            // 0..7
        const int pg = cc >> 2, kbl = cc & 3;
        const bf16x8 vv = *(const bf16x8*)&Lt[(pg*32 + ln31)*72 + kbl*16 + half*8];
        const size_t chunk = (size_t)((px0>>5) + pg)*16 + kbase + kbl;
        *(bf16x8*)&dst[(chunk<<9) + lane*8] = vv;
      }
    } else {
      const int ocv0 = (ot-8)*64 + ocl;
      float* vb = V + (((size_t)(src*8 + b)*128) << 10) + hw0;
      #pragma unroll
      for (int lg = 0; lg < 4; lg++) {
        vb[(size_t)(ocv0+0)*1024 + lg*16 + mrow] = acc[lg][0] + bias4.x;
        vb[(size_t)(ocv0+1)*1024 + lg*16 + mrow] = acc[lg][1] + bias4.y;
        vb[(size_t)(ocv0+2)*1024 + lg*16 + mrow] = acc[lg][2] + bias4.z;
        vb[(size_t)(ocv0+3)*1024 + lg*16 + mrow] = acc[lg][3] + bias4.w;
      }
    }
  }
}

// ---------------------------------------------------------------------------
// K3: 32x32x16 MFMA, NO LDS, NO BARRIERS.  Block = 256 rows x one key-batch;
//   each of 4 waves owns 64 rows (2 row-grps) and streams ALL K fragments
//   direct global->VGPR (L1/L2-served; 64 consecutive blocks share the same
//   512 KB K-slice -> XCD-L2 resident).  Quarter-cg (4-frag) ping-pong
//   register pipeline; compiler emits fine-grained vmcnt per buffer.
//   Q frags in registers (128 VGPR).  Pm layout: [batch(16)][row(16384)]
// ---------------------------------------------------------------------------
#define LDK(cg, kb) (*(const bf16x8*)(kp + (((size_t)(cg)*16 + (kb)) << 9)))

__global__ __launch_bounds__(256, 2) void k3_smax(
    const ushort_t* __restrict__ Qf, const ushort_t* __restrict__ Kf,
    float* __restrict__ Pm)
{
  const int tid = threadIdx.x;
  const int bt = blockIdx.x >> 6;      // key-batch 0..15
  const int rt = blockIdx.x & 63;      // row-tile (256 rows)
  const int w = tid >> 6, lane = tid & 63;
  const int ln31 = lane & 31, half = lane >> 5;

  const int rgb = rt*8 + w*2;          // wave's first row-grp32
  const ushort_t* kp = Kf + (((size_t)bt*32*16) << 9) + lane*8;

  // Q fragments: loaded once, live whole kernel (128 VGPR)
  bf16x8 qf[2][16];
  #pragma unroll
  for (int rg = 0; rg < 2; rg++)
    #pragma unroll
    for (int kb = 0; kb < 16; kb++)
      qf[rg][kb] = *(const bf16x8*)&Qf[((size_t)((rgb + rg)*16 + kb)<<9) + lane*8];

  f32x16 rmax0, rmax1;
  #pragma unroll
  for (int i = 0; i < 16; i++) { rmax0[i] = -3.4e38f; rmax1[i] = -3.4e38f; }

  bf16x8 bX[4], bY[4];
  #pragma unroll
  for (int i = 0; i < 4; i++) bX[i] = LDK(0, i);

  for (int cg = 0; cg < 32; cg++) {
    f32x16 a0 = zero16(), a1 = zero16();

    #pragma unroll
    for (int i = 0; i < 4; i++) bY[i] = LDK(cg, 4 + i);
    #pragma unroll
    for (int kb = 0; kb < 4; kb++) {
      a0 = __builtin_amdgcn_mfma_f32_32x32x16_bf16(qf[0][kb], bX[kb], a0, 0, 0, 0);
      a1 = __builtin_amdgcn_mfma_f32_32x32x16_bf16(qf[1][kb], bX[kb], a1, 0, 0, 0);
    }

    #pragma unroll
    for (int i = 0; i < 4; i++) bX[i] = LDK(cg, 8 + i);
    #pragma unroll
    for (int kb = 4; kb < 8; kb++) {
      a0 = __builtin_amdgcn_mfma_f32_32x32x16_bf16(qf[0][kb], bY[kb-4], a0, 0, 0, 0);
      a1 = __builtin_amdgcn_mfma_f32_32x32x16_bf16(qf[1][kb], bY[kb-4], a1, 0, 0, 0);
    }

    #pragma unroll
    for (int i = 0; i < 4; i++) bY[i] = LDK(cg, 12 + i);
    #pragma unroll
    for (int kb = 8; kb < 12; kb++) {
      a0 = __builtin_amdgcn_mfma_f32_32x32x16_bf16(qf[0][kb], bX[kb-8], a0, 0, 0, 0);
      a1 = __builtin_amdgcn_mfma_f32_32x32x16_bf16(qf[1][kb], bX[kb-8], a1, 0, 0, 0);
    }

    if (cg < 31) {
      #pragma unroll
      for (int i = 0; i < 4; i++) bX[i] = LDK(cg + 1, i);
    }
    #pragma unroll
    for (int kb = 12; kb < 16; kb++) {
      a0 = __builtin_amdgcn_mfma_f32_32x32x16_bf16(qf[0][kb], bY[kb-12], a0, 0, 0, 0);
      a1 = __builtin_amdgcn_mfma_f32_32x32x16_bf16(qf[1][kb], bY[kb-12], a1, 0, 0, 0);
    }

    #pragma unroll
    for (int i = 0; i < 16; i++) {
      rmax0[i] = fmaxf(rmax0[i], a0[i]);
      rmax1[i] = fmaxf(rmax1[i], a1[i]);
    }
  }

  // epilogue: per-row max over 32 cols (5 xor-shuffles within each 32-lane half)
  // C/D: col = lane&31, row = (reg&3) + 8*(reg>>2) + 4*half  (m74/m101)
  #pragma unroll
  for (int rg = 0; rg < 2; rg++) {
    #pragma unroll
    for (int e = 0; e < 16; e++) {
      float v = (rg == 0) ? rmax0[e] : rmax1[e];
      v = fmaxf(v, __shfl_xor(v, 1));
      v = fmaxf(v, __shfl_xor(v, 2));
      v = fmaxf(v, __shfl_xor(v, 4));
      v = fmaxf(v, __shfl_xor(v, 8));
      v = fmaxf(v, __shfl_xor(v, 16));
      if (ln31 == 0) {
        const int row = rt*256 + w*64 + rg*32 + (e&3) + 8*(e>>2) + 4*half;
        Pm[(size_t)bt*16384 + row] = v;
      }
    }
  }
}

// ---------------------------------------------------------------------------
// K4: per-row logits from batch-maxes + softmax over hw -> gates G[4][8][1024]
// ---------------------------------------------------------------------------
__global__ __launch_bounds__(1024) void k4_gates(
    const float* __restrict__ Pm, float* __restrict__ G)
{
  __shared__ float red[1024];
  const int tid = threadIdx.x;
  const int qset = blockIdx.x >> 3, b = blockIdx.x & 7;
  const int i = qset*8192 + b*1024 + tid;

  float ma = 0.f, mb = 0.f;
  #pragma unroll
  for (int bt = 0; bt < 8; bt++)  ma += Pm[(size_t)bt*16384 + i];
  #pragma unroll
  for (int bt = 8; bt < 16; bt++) mb += Pm[(size_t)bt*16384 + i];
  const float sc = 0.125f * 0.0625f;   // mean over 8 batches * 1/sqrt(256)
  const float la = ma * sc, lb = mb * sc;

  red[tid] = la; __syncthreads();
  for (int s = 512; s > 0; s >>= 1) { if (tid < s) red[tid] = fmaxf(red[tid], red[tid+s]); __syncthreads(); }
  const float Ma = red[0]; __syncthreads();
  const float ea = expf(la - Ma);
  red[tid] = ea; __syncthreads();
  for (int s = 512; s > 0; s >>= 1) { if (tid < s) red[tid] += red[tid+s]; __syncthreads(); }
  const float ga = ea / red[0]; __syncthreads();

  red[tid] = lb; __syncthreads();
  for (int s = 512; s > 0; s >>= 1) { if (tid < s) red[tid] = fmaxf(red[tid], red[tid+s]); __syncthreads(); }
  const float Mb = red[0]; __syncthreads();
  const float eb = expf(lb - Mb);
  red[tid] = eb; __syncthreads();
  for (int s = 512; s > 0; s >>= 1) { if (tid < s) red[tid] += red[tid+s]; __syncthreads(); }
  const float gb = eb / red[0];

  G[(size_t)(qset*2 + 0)*8192 + b*1024 + tid] = ga;
  G[(size_t)(qset*2 + 1)*8192 + b*1024 + tid] = gb;
}

// ---------------------------------------------------------------------------
// K5: out[b][ch][hw] = gate * V + b128.  ch blocks: [x34 | a_x4 | x43 | b_x3]
// ---------------------------------------------------------------------------
__global__ __launch_bounds__(256) void k5_out(
    const float* __restrict__ V, const float* __restrict__ G,
    const float* __restrict__ b128, float* __restrict__ out)
{
  const int idx = blockIdx.x*256 + threadIdx.x;
  const int flat = idx << 2;
  const int hw = flat & 1023;
  const int ch = (flat >> 10) & 511;
  const int b  = flat >> 19;
  const int blk = ch >> 7, o = ch & 127;
  const int gidx = (blk == 0) ? 2 : (blk == 1) ? 0 : (blk == 2) ? 1 : 3;
  const int src = (blk >= 2) ? 1 : 0;

  const float4 v = *(const float4*)&V[((size_t)((src*8 + b)*128 + o) << 10) + hw];
  const float4 g = *(const float4*)&G[(size_t)gidx*8192 + b*1024 + hw];
  const float bias = b128[o];
  float4 r;
  r.x = g.x*v.x + bias; r.y = g.y*v.y + bias;
  r.z = g.z*v.z + bias; r.w = g.w*v.w + bias;
  *(float4*)&out[flat] = r;
}

// ---------------------------------------------------------------------------
extern "C" void kernel_launch(void* const* d_in, const int* in_sizes, int n_in,
                              void* d_out, int out_size, void* d_ws, size_t ws_size,
                              hipStream_t stream)
{
  const float* x4   = (const float*)d_in[0];
  const float* x3   = (const float*)d_in[1];
  const float* wq   = (const float*)d_in[2];
  const float* bq   = (const float*)d_in[3];
  const float* wk   = (const float*)d_in[4];
  const float* bk   = (const float*)d_in[5];
  const float* wv   = (const float*)d_in[6];
  const float* bv   = (const float*)d_in[7];
  const float* w128 = (const float*)d_in[8];
  const float* b128 = (const float*)d_in[9];
  float* out = (float*)d_out;

  char* ws = (char*)d_ws;
  ushort_t* Qf = (ushort_t*)ws;  ws += (size_t)16384*256*2;     // 8 MB
  ushort_t* Kf = (ushort_t*)ws;  ws += (size_t)16384*256*2;     // 8 MB
  float*    V  = (float*)ws;     ws += (size_t)2*8*128*1024*4;  // 8 MB
  float*    Pm = (float*)ws;     ws += (size_t)16*16384*4;      // 1 MB
  ushort_t* Wf = (ushort_t*)ws;  ws += (size_t)640*256*2;       // 320 KB
  float* bias_all = (float*)ws;  ws += 640*4;
  float*    G  = (float*)ws;                                    // 128 KB

  k1_weights <<<544,  256, 0, stream>>>(wq, bq, wk, bk, wv, bv, w128, Wf, bias_all);
  k2_features<<<256,  256, 0, stream>>>(x4, x3, Wf, bias_all, Qf, Kf, V);
  k3_smax    <<<1024, 256, 0, stream>>>(Qf, Kf, Pm);
  k4_gates   <<<16,  1024, 0, stream>>>(Pm, G);
  k5_out     <<<4096, 256, 0, stream>>>(V, G, b128, out);
}

// Round 6
// 215.742 us; speedup vs baseline: 1.3106x; 1.3106x over previous
//
#include <hip/hip_runtime.h>

typedef unsigned short ushort_t;
typedef unsigned char uchar_t;
typedef unsigned long u64_t;
typedef __attribute__((ext_vector_type(8))) short bf16x8;
typedef __attribute__((ext_vector_type(4))) float f32x4;
typedef __attribute__((ext_vector_type(16))) float f32x16;

__device__ __forceinline__ unsigned short f2bf(float f) {
  union { float f; unsigned int u; } v; v.f = f;
  unsigned int r = v.u + 0x7FFFu + ((v.u >> 16) & 1u);
  return (unsigned short)(r >> 16);
}

__device__ __forceinline__ float bf2f(unsigned short u) {
  union { unsigned int i; float f; } v; v.i = ((unsigned int)u) << 16;
  return v.f;
}

__device__ __forceinline__ void gl_lds16(const void* gsrc, void* ldst) {
  __builtin_amdgcn_global_load_lds(
      (const __attribute__((address_space(1))) void*)gsrc,
      (__attribute__((address_space(3))) void*)ldst, 16, 0, 0);
}

__device__ __forceinline__ f32x16 zero16() {
  f32x16 z;
  #pragma unroll
  for (int i = 0; i < 16; i++) z[i] = 0.f;
  return z;
}

__device__ __forceinline__ int frag_idx(int oc, int ci) {
  return (((oc>>4)*8 + (ci>>5))<<9) + ((((ci>>3)&3)*16 + (oc&15))<<3) + (ci&7);
}

// ---------------------------------------------------------------------------
// K1: fragment-major bf16 weight bank Wf[640][256] (Q=wq, K=wk, V=w128@wv)
//     + bias_all[640].  Blocks 0..511: copy/cast QK.  512..543: V-fold (4 oc).
// ---------------------------------------------------------------------------
__global__ __launch_bounds__(256) void k1_weights(
    const float* __restrict__ wq, const float* __restrict__ bq,
    const float* __restrict__ wk, const float* __restrict__ bk,
    const float* __restrict__ wv, const float* __restrict__ bv,
    const float* __restrict__ w128,
    ushort_t* __restrict__ Wf, float* __restrict__ bias_all)
{
  const int ci = threadIdx.x;
  if (blockIdx.x < 512) {
    const int oc = blockIdx.x;
    const float v = (oc < 256) ? wq[oc*256 + ci] : wk[(oc-256)*256 + ci];
    Wf[frag_idx(oc, ci)] = f2bf(v);
    if (ci == 0) bias_all[oc] = (oc < 256) ? bq[oc] : bk[oc-256];
  } else {
    const int og = (blockIdx.x - 512) * 4;
    float a0 = 0.f, a1 = 0.f, a2 = 0.f, a3 = 0.f;
    for (int co = 0; co < 256; co++) {
      const float wvv = wv[co*256 + ci];
      a0 += w128[(og+0)*256 + co] * wvv;
      a1 += w128[(og+1)*256 + co] * wvv;
      a2 += w128[(og+2)*256 + co] * wvv;
      a3 += w128[(og+3)*256 + co] * wvv;
    }
    Wf[frag_idx(512+og+0, ci)] = f2bf(a0);
    Wf[frag_idx(512+og+1, ci)] = f2bf(a1);
    Wf[frag_idx(512+og+2, ci)] = f2bf(a2);
    Wf[frag_idx(512+og+3, ci)] = f2bf(a3);
    if (ci < 4) {
      float s = 0.f;
      for (int co = 0; co < 256; co++) s += w128[(og+ci)*256 + co] * bv[co];
      bias_all[512 + og + ci] = s;
    }
  }
}

// ---------------------------------------------------------------------------
// K2: MFMA feature GEMM (bf16 16x16x32 internally). 256 blocks = 64-px tiles.
//   ot 0..3 -> Qf8, 4..7 -> Kf8: fp8 e4m3 chunks for 32x32x16_fp8_fp8:
//     chunk(g, kp) = 1 KB; lane holds rows g*32+(lane&31);
//     byte j   -> k = kp*32 +      (lane>>5)*8 + j   (lo u64, kb even)
//     byte 8+j -> k = kp*32 + 16 + (lane>>5)*8 + j   (hi u64, kb odd)
//   ot 8..9 -> V fp32 [src*8+b][oc][hw]
// ---------------------------------------------------------------------------
__global__ __launch_bounds__(256) void k2_features(
    const float* __restrict__ x4, const float* __restrict__ x3,
    const ushort_t* __restrict__ Wf, const float* __restrict__ bias_all,
    uchar_t* __restrict__ Qf8, uchar_t* __restrict__ Kf8, float* __restrict__ V)
{
  __shared__ ushort_t Af[32*512];      // 32 KB
  __shared__ ushort_t Wl[2][32*512];   // 2 x 32 KB
  __shared__ ushort_t Lt[64*72];       // repack buffer (bf16)

  const int tid = threadIdx.x;
  const int w = tid >> 6, lane = tid & 63;
  const int mrow = lane & 15, quad = lane >> 4;
  const int ln31 = lane & 31, half = lane >> 5;

  const int px0 = blockIdx.x * 64;
  const int src = px0 >> 13, b = (px0 >> 10) & 7, hw0 = px0 & 1023;
  const float* xp = (src ? x3 : x4) + (size_t)b*262144;

  for (int kb = 0; kb < 8; kb++)
    gl_lds16(Wf + ((size_t)((0*4 + w)*8 + kb)<<9) + lane*8, &Wl[0][(w*8+kb)*512]);

  {
    const int hw = hw0 + w*16 + mrow;
    for (int kb = 0; kb < 8; kb++) {
      const int ch0 = kb*32 + quad*8;
      bf16x8 pk;
      #pragma unroll
      for (int j = 0; j < 8; j++)
        ((ushort_t*)&pk)[j] = f2bf(xp[(size_t)(ch0 + j)*1024 + hw]);
      *(bf16x8*)&Af[(w*8 + kb)*512 + lane*8] = pk;
    }
  }
  __syncthreads();

  for (int ot = 0; ot < 10; ot++) {
    const int nbuf = (ot+1) & 1, cbuf = ot & 1;
    if (ot < 9)
      for (int kb = 0; kb < 8; kb++)
        gl_lds16(Wf + ((size_t)(((ot+1)*4 + w)*8 + kb)<<9) + lane*8,
                 &Wl[nbuf][(w*8+kb)*512]);
    asm volatile("s_waitcnt vmcnt(8)" ::: "memory");

    f32x4 acc[4];
    #pragma unroll
    for (int lg = 0; lg < 4; lg++) acc[lg] = (f32x4){0.f,0.f,0.f,0.f};
    #pragma unroll
    for (int kb = 0; kb < 8; kb++) {
      const bf16x8 a = *(const bf16x8*)&Wl[cbuf][(w*8 + kb)*512 + lane*8];
      #pragma unroll
      for (int lg = 0; lg < 4; lg++) {
        const bf16x8 bx = *(const bf16x8*)&Af[(lg*8 + kb)*512 + lane*8];
        acc[lg] = __builtin_amdgcn_mfma_f32_16x16x32_bf16(a, bx, acc[lg], 0, 0, 0);
      }
    }
    const int ocl = w*16 + quad*4;
    const float4 bias4 = *(const float4*)&bias_all[ot*64 + ocl];

    if (ot < 8) {
      __syncthreads();
      #pragma unroll
      for (int lg = 0; lg < 4; lg++) {
        const int px = lg*16 + mrow;
        ushort4 pk;
        pk.x = f2bf(acc[lg][0] + bias4.x);
        pk.y = f2bf(acc[lg][1] + bias4.y);
        pk.z = f2bf(acc[lg][2] + bias4.z);
        pk.w = f2bf(acc[lg][3] + bias4.w);
        *(ushort4*)&Lt[px*72 + ocl] = pk;
      }
      __syncthreads();
      // emit one fp8 chunk per wave: wave w -> g = w>>1, e = w&1
      const int g = w >> 1, e = w & 1;
      const int row = g*32 + ln31;
      const ushort_t* lp = &Lt[row*72 + e*32 + half*8];
      float fl[8], fh[8];
      #pragma unroll
      for (int j = 0; j < 8; j++) { fl[j] = bf2f(lp[j]); fh[j] = bf2f(lp[16+j]); }
      int w0 = __builtin_amdgcn_cvt_pk_fp8_f32(fl[0], fl[1], 0, 0);
      w0     = __builtin_amdgcn_cvt_pk_fp8_f32(fl[2], fl[3], w0, 1);
      int w1 = __builtin_amdgcn_cvt_pk_fp8_f32(fl[4], fl[5], 0, 0);
      w1     = __builtin_amdgcn_cvt_pk_fp8_f32(fl[6], fl[7], w1, 1);
      int w2 = __builtin_amdgcn_cvt_pk_fp8_f32(fh[0], fh[1], 0, 0);
      w2     = __builtin_amdgcn_cvt_pk_fp8_f32(fh[2], fh[3], w2, 1);
      int w3 = __builtin_amdgcn_cvt_pk_fp8_f32(fh[4], fh[5], 0, 0);
      w3     = __builtin_amdgcn_cvt_pk_fp8_f32(fh[6], fh[7], w3, 1);
      uchar_t* dst = (ot < 4) ? Qf8 : Kf8;
      const size_t chunk = (size_t)((px0>>5) + g)*8 + (ot&3)*2 + e;
      int4 pk4; pk4.x = w0; pk4.y = w1; pk4.z = w2; pk4.w = w3;
      *(int4*)(dst + (chunk<<10) + lane*16) = pk4;
    } else {
      const int ocv0 = (ot-8)*64 + ocl;
      float* vb = V + (((size_t)(src*8 + b)*128) << 10) + hw0;
      #pragma unroll
      for (int lg = 0; lg < 4; lg++) {
        vb[(size_t)(ocv0+0)*1024 + lg*16 + mrow] = acc[lg][0] + bias4.x;
        vb[(size_t)(ocv0+1)*1024 + lg*16 + mrow] = acc[lg][1] + bias4.y;
        vb[(size_t)(ocv0+2)*1024 + lg*16 + mrow] = acc[lg][2] + bias4.z;
        vb[(size_t)(ocv0+3)*1024 + lg*16 + mrow] = acc[lg][3] + bias4.w;
      }
    }
  }
}

// ---------------------------------------------------------------------------
// K3: fp8 32x32x16 MFMA.  Block = 256 rows x one key-batch (1024 cols).
//   4 waves x 64 rows (2 row-grps).  Q frags in regs (64 VGPR).  K staged via
//   gl_lds in 16 KB double-buffered stages (2 cg32 x 8 kp-chunks of 1 KB),
//   16 stages, col sweep rotated by block parity (max is order-free).
//   Pm layout: [batch(16)][row(16384)]
// ---------------------------------------------------------------------------
__global__ __launch_bounds__(256, 2) void k3_smax(
    const uchar_t* __restrict__ Qf8, const uchar_t* __restrict__ Kf8,
    float* __restrict__ Pm)
{
  __shared__ __align__(16) uchar_t Kl[2][16384];   // 2 x 16 KB

  const int tid = threadIdx.x;
  const int bt = blockIdx.x >> 6;      // key-batch 0..15
  const int rt = blockIdx.x & 63;      // row-tile (256 rows)
  const int w = tid >> 6, lane = tid & 63;
  const int ln31 = lane & 31, half = lane >> 5;

  const int rgb = rt*8 + w*2;          // wave's first row-grp32
  const int g0 = (blockIdx.x & 1) * 8; // stage-phase rotation

  // prologue: stage s=0 (actual cg-pair g0): 16 chunks, wave w -> c = w*4..+3
  #pragma unroll
  for (int q = 0; q < 4; q++) {
    const int c = w*4 + q;             // cgl = c>>3, kp = c&7
    gl_lds16(Kf8 + (((size_t)(bt*32 + g0*2 + (c>>3))*8 + (c&7))<<10) + lane*16,
             &Kl[0][c*1024]);
  }

  // Q fragments: 2 rg x 16 kb halves = 64 VGPR, resident whole kernel
  u64_t qf[2][16];
  #pragma unroll
  for (int rg = 0; rg < 2; rg++)
    #pragma unroll
    for (int kp = 0; kp < 8; kp++) {
      const ulonglong2 qv = *(const ulonglong2*)(
          Qf8 + (((size_t)(rgb + rg)*8 + kp)<<10) + lane*16);
      qf[rg][2*kp] = qv.x; qf[rg][2*kp+1] = qv.y;
    }

  f32x16 rmax0, rmax1;
  #pragma unroll
  for (int i = 0; i < 16; i++) { rmax0[i] = -3.4e38f; rmax1[i] = -3.4e38f; }

  for (int s = 0; s < 16; s++) {
    __syncthreads();                   // drains prefetch for stage s
    if (s < 15) {
      const int gn = (s + 1 + g0) & 15;
      #pragma unroll
      for (int q = 0; q < 4; q++) {
        const int c = w*4 + q;
        gl_lds16(Kf8 + (((size_t)(bt*32 + gn*2 + (c>>3))*8 + (c&7))<<10) + lane*16,
                 &Kl[(s+1)&1][c*1024]);
      }
    }
    const uchar_t* kl = Kl[s & 1];
    #pragma unroll
    for (int cgl = 0; cgl < 2; cgl++) {
      f32x16 a0 = zero16(), a1 = zero16();
      #pragma unroll
      for (int kp = 0; kp < 8; kp++) {
        const ulonglong2 kc = *(const ulonglong2*)&kl[(cgl*8 + kp)*1024 + lane*16];
        a0 = __builtin_amdgcn_mfma_f32_32x32x16_fp8_fp8((long)qf[0][2*kp],   (long)kc.x, a0, 0, 0, 0);
        a1 = __builtin_amdgcn_mfma_f32_32x32x16_fp8_fp8((long)qf[1][2*kp],   (long)kc.x, a1, 0, 0, 0);
        a0 = __builtin_amdgcn_mfma_f32_32x32x16_fp8_fp8((long)qf[0][2*kp+1], (long)kc.y, a0, 0, 0, 0);
        a1 = __builtin_amdgcn_mfma_f32_32x32x16_fp8_fp8((long)qf[1][2*kp+1], (long)kc.y, a1, 0, 0, 0);
      }
      #pragma unroll
      for (int i = 0; i < 16; i++) {
        rmax0[i] = fmaxf(rmax0[i], a0[i]);
        rmax1[i] = fmaxf(rmax1[i], a1[i]);
      }
    }
  }

  // epilogue: per-row max over 32 cols (5 xor-shuffles in each 32-lane half)
  // C/D: col = lane&31, row = (reg&3) + 8*(reg>>2) + 4*half (shape-determined)
  #pragma unroll
  for (int rg = 0; rg < 2; rg++) {
    #pragma unroll
    for (int e = 0; e < 16; e++) {
      float v = (rg == 0) ? rmax0[e] : rmax1[e];
      v = fmaxf(v, __shfl_xor(v, 1));
      v = fmaxf(v, __shfl_xor(v, 2));
      v = fmaxf(v, __shfl_xor(v, 4));
      v = fmaxf(v, __shfl_xor(v, 8));
      v = fmaxf(v, __shfl_xor(v, 16));
      if (ln31 == 0) {
        const int row = rt*256 + w*64 + rg*32 + (e&3) + 8*(e>>2) + 4*half;
        Pm[(size_t)bt*16384 + row] = v;
      }
    }
  }
}

// ---------------------------------------------------------------------------
// K4: per-row logits from batch-maxes + softmax over hw -> gates G[4][8][1024]
// ---------------------------------------------------------------------------
__global__ __launch_bounds__(1024) void k4_gates(
    const float* __restrict__ Pm, float* __restrict__ G)
{
  __shared__ float red[1024];
  const int tid = threadIdx.x;
  const int qset = blockIdx.x >> 3, b = blockIdx.x & 7;
  const int i = qset*8192 + b*1024 + tid;

  float ma = 0.f, mb = 0.f;
  #pragma unroll
  for (int bt = 0; bt < 8; bt++)  ma += Pm[(size_t)bt*16384 + i];
  #pragma unroll
  for (int bt = 8; bt < 16; bt++) mb += Pm[(size_t)bt*16384 + i];
  const float sc = 0.125f * 0.0625f;   // mean over 8 batches * 1/sqrt(256)
  const float la = ma * sc, lb = mb * sc;

  red[tid] = la; __syncthreads();
  for (int s = 512; s > 0; s >>= 1) { if (tid < s) red[tid] = fmaxf(red[tid], red[tid+s]); __syncthreads(); }
  const float Ma = red[0]; __syncthreads();
  const float ea = expf(la - Ma);
  red[tid] = ea; __syncthreads();
  for (int s = 512; s > 0; s >>= 1) { if (tid < s) red[tid] += red[tid+s]; __syncthreads(); }
  const float ga = ea / red[0]; __syncthreads();

  red[tid] = lb; __syncthreads();
  for (int s = 512; s > 0; s >>= 1) { if (tid < s) red[tid] = fmaxf(red[tid], red[tid+s]); __syncthreads(); }
  const float Mb = red[0]; __syncthreads();
  const float eb = expf(lb - Mb);
  red[tid] = eb; __syncthreads();
  for (int s = 512; s > 0; s >>= 1) { if (tid < s) red[tid] += red[tid+s]; __syncthreads(); }
  const float gb = eb / red[0];

  G[(size_t)(qset*2 + 0)*8192 + b*1024 + tid] = ga;
  G[(size_t)(qset*2 + 1)*8192 + b*1024 + tid] = gb;
}

// ---------------------------------------------------------------------------
// K5: out[b][ch][hw] = gate * V + b128.  ch blocks: [x34 | a_x4 | x43 | b_x3]
// ---------------------------------------------------------------------------
__global__ __launch_bounds__(256) void k5_out(
    const float* __restrict__ V, const float* __restrict__ G,
    const float* __restrict__ b128, float* __restrict__ out)
{
  const int idx = blockIdx.x*256 + threadIdx.x;
  const int flat = idx << 2;
  const int hw = flat & 1023;
  const int ch = (flat >> 10) & 511;
  const int b  = flat >> 19;
  const int blk = ch >> 7, o = ch & 127;
  const int gidx = (blk == 0) ? 2 : (blk == 1) ? 0 : (blk == 2) ? 1 : 3;
  const int src = (blk >= 2) ? 1 : 0;

  const float4 v = *(const float4*)&V[((size_t)((src*8 + b)*128 + o) << 10) + hw];
  const float4 g = *(const float4*)&G[(size_t)gidx*8192 + b*1024 + hw];
  const float bias = b128[o];
  float4 r;
  r.x = g.x*v.x + bias; r.y = g.y*v.y + bias;
  r.z = g.z*v.z + bias; r.w = g.w*v.w + bias;
  *(float4*)&out[flat] = r;
}

// ---------------------------------------------------------------------------
extern "C" void kernel_launch(void* const* d_in, const int* in_sizes, int n_in,
                              void* d_out, int out_size, void* d_ws, size_t ws_size,
                              hipStream_t stream)
{
  const float* x4   = (const float*)d_in[0];
  const float* x3   = (const float*)d_in[1];
  const float* wq   = (const float*)d_in[2];
  const float* bq   = (const float*)d_in[3];
  const float* wk   = (const float*)d_in[4];
  const float* bk   = (const float*)d_in[5];
  const float* wv   = (const float*)d_in[6];
  const float* bv   = (const float*)d_in[7];
  const float* w128 = (const float*)d_in[8];
  const float* b128 = (const float*)d_in[9];
  float* out = (float*)d_out;

  char* ws = (char*)d_ws;
  uchar_t*  Qf8 = (uchar_t*)ws;  ws += (size_t)512*8*1024;      // 4 MB
  uchar_t*  Kf8 = (uchar_t*)ws;  ws += (size_t)512*8*1024;      // 4 MB
  float*    V   = (float*)ws;    ws += (size_t)2*8*128*1024*4;  // 8 MB
  float*    Pm  = (float*)ws;    ws += (size_t)16*16384*4;      // 1 MB
  ushort_t* Wf  = (ushort_t*)ws; ws += (size_t)640*256*2;       // 320 KB
  float* bias_all = (float*)ws;  ws += 640*4;
  float*    G   = (float*)ws;                                   // 128 KB

  k1_weights <<<544,  256, 0, stream>>>(wq, bq, wk, bk, wv, bv, w128, Wf, bias_all);
  k2_features<<<256,  256, 0, stream>>>(x4, x3, Wf, bias_all, Qf8, Kf8, V);
  k3_smax    <<<1024, 256, 0, stream>>>(Qf8, Kf8, Pm);
  k4_gates   <<<16,  1024, 0, stream>>>(Pm, G);
  k5_out     <<<4096, 256, 0, stream>>>(V, G, b128, out);
}

// Round 7
// 204.151 us; speedup vs baseline: 1.3850x; 1.0568x over previous
//
#include <hip/hip_runtime.h>

typedef unsigned short ushort_t;
typedef unsigned char uchar_t;
typedef unsigned long u64_t;
typedef __attribute__((ext_vector_type(8))) short bf16x8;
typedef __attribute__((ext_vector_type(4))) float f32x4;
typedef __attribute__((ext_vector_type(16))) float f32x16;
typedef __attribute__((ext_vector_type(8))) int v8i;

__device__ __forceinline__ unsigned short f2bf(float f) {
  union { float f; unsigned int u; } v; v.f = f;
  unsigned int r = v.u + 0x7FFFu + ((v.u >> 16) & 1u);
  return (unsigned short)(r >> 16);
}

__device__ __forceinline__ float bf2f(unsigned short u) {
  union { unsigned int i; float f; } v; v.i = ((unsigned int)u) << 16;
  return v.f;
}

__device__ __forceinline__ void gl_lds16(const void* gsrc, void* ldst) {
  __builtin_amdgcn_global_load_lds(
      (const __attribute__((address_space(1))) void*)gsrc,
      (__attribute__((address_space(3))) void*)ldst, 16, 0, 0);
}

__device__ __forceinline__ int frag_idx(int oc, int ci) {
  return (((oc>>4)*8 + (ci>>5))<<9) + ((((ci>>3)&3)*16 + (oc&15))<<3) + (ci&7);
}

// ---------------------------------------------------------------------------
// K1: fragment-major bf16 weight bank Wf[640][256] (Q=wq, K=wk, V=w128@wv)
//     + bias_all[640].  Blocks 0..511: copy/cast QK.  512..543: V-fold (4 oc).
// ---------------------------------------------------------------------------
__global__ __launch_bounds__(256) void k1_weights(
    const float* __restrict__ wq, const float* __restrict__ bq,
    const float* __restrict__ wk, const float* __restrict__ bk,
    const float* __restrict__ wv, const float* __restrict__ bv,
    const float* __restrict__ w128,
    ushort_t* __restrict__ Wf, float* __restrict__ bias_all)
{
  const int ci = threadIdx.x;
  if (blockIdx.x < 512) {
    const int oc = blockIdx.x;
    const float v = (oc < 256) ? wq[oc*256 + ci] : wk[(oc-256)*256 + ci];
    Wf[frag_idx(oc, ci)] = f2bf(v);
    if (ci == 0) bias_all[oc] = (oc < 256) ? bq[oc] : bk[oc-256];
  } else {
    const int og = (blockIdx.x - 512) * 4;
    float a0 = 0.f, a1 = 0.f, a2 = 0.f, a3 = 0.f;
    for (int co = 0; co < 256; co++) {
      const float wvv = wv[co*256 + ci];
      a0 += w128[(og+0)*256 + co] * wvv;
      a1 += w128[(og+1)*256 + co] * wvv;
      a2 += w128[(og+2)*256 + co] * wvv;
      a3 += w128[(og+3)*256 + co] * wvv;
    }
    Wf[frag_idx(512+og+0, ci)] = f2bf(a0);
    Wf[frag_idx(512+og+1, ci)] = f2bf(a1);
    Wf[frag_idx(512+og+2, ci)] = f2bf(a2);
    Wf[frag_idx(512+og+3, ci)] = f2bf(a3);
    if (ci < 4) {
      float s = 0.f;
      for (int co = 0; co < 256; co++) s += w128[(og+ci)*256 + co] * bv[co];
      bias_all[512 + og + ci] = s;
    }
  }
}

// ---------------------------------------------------------------------------
// K2: MFMA feature GEMM (bf16 16x16x32 internally). Grid (256, 2):
//   x = 64-px tile, y splits the output dim: y=0 -> ot 0..4, y=1 -> ot 5..9.
//   ot 0..3 -> Qf8, 4..7 -> Kf8 (fp8 e4m3 chunks, 1 KB each, 16B/lane),
//   ot 8..9 -> V fp32 [src*8+b][oc][hw]
// ---------------------------------------------------------------------------
__global__ __launch_bounds__(256) void k2_features(
    const float* __restrict__ x4, const float* __restrict__ x3,
    const ushort_t* __restrict__ Wf, const float* __restrict__ bias_all,
    uchar_t* __restrict__ Qf8, uchar_t* __restrict__ Kf8, float* __restrict__ V)
{
  __shared__ ushort_t Af[32*512];      // 32 KB
  __shared__ ushort_t Wl[2][32*512];   // 2 x 32 KB
  __shared__ ushort_t Lt[64*72];       // repack buffer (bf16)

  const int tid = threadIdx.x;
  const int w = tid >> 6, lane = tid & 63;
  const int mrow = lane & 15, quad = lane >> 4;
  const int ln31 = lane & 31, half = lane >> 5;

  const int px0 = blockIdx.x * 64;
  const int src = px0 >> 13, b = (px0 >> 10) & 7, hw0 = px0 & 1023;
  const float* xp = (src ? x3 : x4) + (size_t)b*262144;

  const int ot0 = blockIdx.y * 5;      // y=0: ot 0..4, y=1: ot 5..9

  for (int kb = 0; kb < 8; kb++)
    gl_lds16(Wf + ((size_t)((ot0*4 + w)*8 + kb)<<9) + lane*8,
             &Wl[ot0&1][(w*8+kb)*512]);

  {
    const int hw = hw0 + w*16 + mrow;
    for (int kb = 0; kb < 8; kb++) {
      const int ch0 = kb*32 + quad*8;
      bf16x8 pk;
      #pragma unroll
      for (int j = 0; j < 8; j++)
        ((ushort_t*)&pk)[j] = f2bf(xp[(size_t)(ch0 + j)*1024 + hw]);
      *(bf16x8*)&Af[(w*8 + kb)*512 + lane*8] = pk;
    }
  }
  __syncthreads();

  for (int ot = ot0; ot < ot0 + 5; ot++) {
    const int nbuf = (ot+1) & 1, cbuf = ot & 1;
    if (ot + 1 < ot0 + 5) {
      for (int kb = 0; kb < 8; kb++)
        gl_lds16(Wf + ((size_t)(((ot+1)*4 + w)*8 + kb)<<9) + lane*8,
                 &Wl[nbuf][(w*8+kb)*512]);
      asm volatile("s_waitcnt vmcnt(8)" ::: "memory");
    } else {
      asm volatile("s_waitcnt vmcnt(0)" ::: "memory");
    }

    f32x4 acc[4];
    #pragma unroll
    for (int lg = 0; lg < 4; lg++) acc[lg] = (f32x4){0.f,0.f,0.f,0.f};
    #pragma unroll
    for (int kb = 0; kb < 8; kb++) {
      const bf16x8 a = *(const bf16x8*)&Wl[cbuf][(w*8 + kb)*512 + lane*8];
      #pragma unroll
      for (int lg = 0; lg < 4; lg++) {
        const bf16x8 bx = *(const bf16x8*)&Af[(lg*8 + kb)*512 + lane*8];
        acc[lg] = __builtin_amdgcn_mfma_f32_16x16x32_bf16(a, bx, acc[lg], 0, 0, 0);
      }
    }
    const int ocl = w*16 + quad*4;
    const float4 bias4 = *(const float4*)&bias_all[ot*64 + ocl];

    if (ot < 8) {
      __syncthreads();
      #pragma unroll
      for (int lg = 0; lg < 4; lg++) {
        const int px = lg*16 + mrow;
        ushort4 pk;
        pk.x = f2bf(acc[lg][0] + bias4.x);
        pk.y = f2bf(acc[lg][1] + bias4.y);
        pk.z = f2bf(acc[lg][2] + bias4.z);
        pk.w = f2bf(acc[lg][3] + bias4.w);
        *(ushort4*)&Lt[px*72 + ocl] = pk;
      }
      __syncthreads();
      // emit one fp8 chunk per wave: wave w -> g = w>>1, e = w&1
      const int g = w >> 1, e = w & 1;
      const int row = g*32 + ln31;
      const ushort_t* lp = &Lt[row*72 + e*32 + half*8];
      float fl[8], fh[8];
      #pragma unroll
      for (int j = 0; j < 8; j++) { fl[j] = bf2f(lp[j]); fh[j] = bf2f(lp[16+j]); }
      int w0 = __builtin_amdgcn_cvt_pk_fp8_f32(fl[0], fl[1], 0, 0);
      w0     = __builtin_amdgcn_cvt_pk_fp8_f32(fl[2], fl[3], w0, 1);
      int w1 = __builtin_amdgcn_cvt_pk_fp8_f32(fl[4], fl[5], 0, 0);
      w1     = __builtin_amdgcn_cvt_pk_fp8_f32(fl[6], fl[7], w1, 1);
      int w2 = __builtin_amdgcn_cvt_pk_fp8_f32(fh[0], fh[1], 0, 0);
      w2     = __builtin_amdgcn_cvt_pk_fp8_f32(fh[2], fh[3], w2, 1);
      int w3 = __builtin_amdgcn_cvt_pk_fp8_f32(fh[4], fh[5], 0, 0);
      w3     = __builtin_amdgcn_cvt_pk_fp8_f32(fh[6], fh[7], w3, 1);
      uchar_t* dst = (ot < 4) ? Qf8 : Kf8;
      const size_t chunk = (size_t)((px0>>5) + g)*8 + (ot&3)*2 + e;
      int4 pk4; pk4.x = w0; pk4.y = w1; pk4.z = w2; pk4.w = w3;
      *(int4*)(dst + (chunk<<10) + lane*16) = pk4;
    } else {
      const int ocv0 = (ot-8)*64 + ocl;
      float* vb = V + (((size_t)(src*8 + b)*128) << 10) + hw0;
      #pragma unroll
      for (int lg = 0; lg < 4; lg++) {
        vb[(size_t)(ocv0+0)*1024 + lg*16 + mrow] = acc[lg][0] + bias4.x;
        vb[(size_t)(ocv0+1)*1024 + lg*16 + mrow] = acc[lg][1] + bias4.y;
        vb[(size_t)(ocv0+2)*1024 + lg*16 + mrow] = acc[lg][2] + bias4.z;
        vb[(size_t)(ocv0+3)*1024 + lg*16 + mrow] = acc[lg][3] + bias4.w;
      }
    }
  }
}

// ---------------------------------------------------------------------------
// K3: MX-scaled fp8 MFMA 32x32x64 (unit scales = plain fp8 at 2x rate).
//   Block = 256 rows x one key-batch (1024 cols), 4 waves x 64 rows.
//   A/B fragments = concat of two consecutive kp-chunks (k-permutation
//   invariance: Q and K use the identical chunk stream, so the HW's internal
//   byte->k map cancels in Q.K).  K staged via gl_lds in 32 KB double-buffered
//   stages (4 cg32 x 8 kp), 8 barriers/block.  Q in regs (64 VGPR).
//   Pm layout: [batch(16)][row(16384)]
// ---------------------------------------------------------------------------
__global__ __launch_bounds__(256, 2) void k3_smax(
    const uchar_t* __restrict__ Qf8, const uchar_t* __restrict__ Kf8,
    float* __restrict__ Pm)
{
  __shared__ __align__(16) uchar_t Kl[2][32768];   // 2 x 32 KB

  const int tid = threadIdx.x;
  const int bt = blockIdx.x >> 6;      // key-batch 0..15
  const int rt = blockIdx.x & 63;      // row-tile (256 rows)
  const int w = tid >> 6, lane = tid & 63;
  const int ln31 = lane & 31, half = lane >> 5;

  const int rgb = rt*8 + w*2;          // wave's first row-grp32
  const int ph = (blockIdx.x & 1)*4;   // stage-phase rotation (8 stages)

  // prologue: stage s=0: 32 chunks (4 cgl x 8 kp); wave w -> c = w*8..w*8+7
  #pragma unroll
  for (int q = 0; q < 8; q++) {
    const int c = w*8 + q;             // cgl = c>>3, kp = c&7
    const int cg = bt*32 + ph*4 + (c>>3);
    gl_lds16(Kf8 + (((size_t)cg*8 + (c&7))<<10) + lane*16, &Kl[0][c*1024]);
  }

  // Q fragments: 2 rg x 4 u-windows, v8i each (64 VGPR), resident whole kernel
  v8i qa[2][4];
  #pragma unroll
  for (int rg = 0; rg < 2; rg++)
    #pragma unroll
    for (int u = 0; u < 4; u++) {
      const int4 p0 = *(const int4*)(Qf8 + (((size_t)(rgb + rg)*8 + 2*u+0)<<10) + lane*16);
      const int4 p1 = *(const int4*)(Qf8 + (((size_t)(rgb + rg)*8 + 2*u+1)<<10) + lane*16);
      qa[rg][u] = (v8i){p0.x, p0.y, p0.z, p0.w, p1.x, p1.y, p1.z, p1.w};
    }

  f32x16 zv;
  #pragma unroll
  for (int i = 0; i < 16; i++) zv[i] = 0.f;
  f32x16 rmax0 = zv, rmax1 = zv;
  #pragma unroll
  for (int i = 0; i < 16; i++) { rmax0[i] = -3.4e38f; rmax1[i] = -3.4e38f; }

  for (int s = 0; s < 8; s++) {
    __syncthreads();                   // drains prefetch for stage s
    if (s < 7) {
      const int sn = (s + 1 + ph) & 7;
      #pragma unroll
      for (int q = 0; q < 8; q++) {
        const int c = w*8 + q;
        const int cg = bt*32 + sn*4 + (c>>3);
        gl_lds16(Kf8 + (((size_t)cg*8 + (c&7))<<10) + lane*16,
                 &Kl[(s+1)&1][c*1024]);
      }
    }
    const uchar_t* kl = Kl[s & 1];
    #pragma unroll
    for (int cgl = 0; cgl < 4; cgl++) {
      v8i bu[4];
      #pragma unroll
      for (int u = 0; u < 4; u++) {
        const int4 b0 = *(const int4*)&kl[(cgl*8 + 2*u+0)*1024 + lane*16];
        const int4 b1 = *(const int4*)&kl[(cgl*8 + 2*u+1)*1024 + lane*16];
        bu[u] = (v8i){b0.x, b0.y, b0.z, b0.w, b1.x, b1.y, b1.z, b1.w};
      }
      f32x16 a0 = __builtin_amdgcn_mfma_scale_f32_32x32x64_f8f6f4(
          qa[0][0], bu[0], zv, 0, 0, 0, 0x7F7F7F7F, 0, 0x7F7F7F7F);
      f32x16 a1 = __builtin_amdgcn_mfma_scale_f32_32x32x64_f8f6f4(
          qa[1][0], bu[0], zv, 0, 0, 0, 0x7F7F7F7F, 0, 0x7F7F7F7F);
      #pragma unroll
      for (int u = 1; u < 4; u++) {
        a0 = __builtin_amdgcn_mfma_scale_f32_32x32x64_f8f6f4(
            qa[0][u], bu[u], a0, 0, 0, 0, 0x7F7F7F7F, 0, 0x7F7F7F7F);
        a1 = __builtin_amdgcn_mfma_scale_f32_32x32x64_f8f6f4(
            qa[1][u], bu[u], a1, 0, 0, 0, 0x7F7F7F7F, 0, 0x7F7F7F7F);
      }
      #pragma unroll
      for (int i = 0; i < 16; i++) {
        rmax0[i] = fmaxf(rmax0[i], a0[i]);
        rmax1[i] = fmaxf(rmax1[i], a1[i]);
      }
    }
  }

  // epilogue: per-row max over 32 cols (5 xor-shuffles in each 32-lane half)
  // C/D: col = lane&31, row = (reg&3) + 8*(reg>>2) + 4*half (shape-determined)
  #pragma unroll
  for (int rg = 0; rg < 2; rg++) {
    #pragma unroll
    for (int e = 0; e < 16; e++) {
      float v = (rg == 0) ? rmax0[e] : rmax1[e];
      v = fmaxf(v, __shfl_xor(v, 1));
      v = fmaxf(v, __shfl_xor(v, 2));
      v = fmaxf(v, __shfl_xor(v, 4));
      v = fmaxf(v, __shfl_xor(v, 8));
      v = fmaxf(v, __shfl_xor(v, 16));
      if (ln31 == 0) {
        const int row = rt*256 + w*64 + rg*32 + (e&3) + 8*(e>>2) + 4*half;
        Pm[(size_t)bt*16384 + row] = v;
      }
    }
  }
}

// ---------------------------------------------------------------------------
// K4: per-row logits from batch-maxes + softmax over hw -> gates G[4][8][1024]
// ---------------------------------------------------------------------------
__global__ __launch_bounds__(1024) void k4_gates(
    const float* __restrict__ Pm, float* __restrict__ G)
{
  __shared__ float red[1024];
  const int tid = threadIdx.x;
  const int qset = blockIdx.x >> 3, b = blockIdx.x & 7;
  const int i = qset*8192 + b*1024 + tid;

  float ma = 0.f, mb = 0.f;
  #pragma unroll
  for (int bt = 0; bt < 8; bt++)  ma += Pm[(size_t)bt*16384 + i];
  #pragma unroll
  for (int bt = 8; bt < 16; bt++) mb += Pm[(size_t)bt*16384 + i];
  const float sc = 0.125f * 0.0625f;   // mean over 8 batches * 1/sqrt(256)
  const float la = ma * sc, lb = mb * sc;

  red[tid] = la; __syncthreads();
  for (int s = 512; s > 0; s >>= 1) { if (tid < s) red[tid] = fmaxf(red[tid], red[tid+s]); __syncthreads(); }
  const float Ma = red[0]; __syncthreads();
  const float ea = expf(la - Ma);
  red[tid] = ea; __syncthreads();
  for (int s = 512; s > 0; s >>= 1) { if (tid < s) red[tid] += red[tid+s]; __syncthreads(); }
  const float ga = ea / red[0]; __syncthreads();

  red[tid] = lb; __syncthreads();
  for (int s = 512; s > 0; s >>= 1) { if (tid < s) red[tid] = fmaxf(red[tid], red[tid+s]); __syncthreads(); }
  const float Mb = red[0]; __syncthreads();
  const float eb = expf(lb - Mb);
  red[tid] = eb; __syncthreads();
  for (int s = 512; s > 0; s >>= 1) { if (tid < s) red[tid] += red[tid+s]; __syncthreads(); }
  const float gb = eb / red[0];

  G[(size_t)(qset*2 + 0)*8192 + b*1024 + tid] = ga;
  G[(size_t)(qset*2 + 1)*8192 + b*1024 + tid] = gb;
}

// ---------------------------------------------------------------------------
// K5: out[b][ch][hw] = gate * V + b128.  ch blocks: [x34 | a_x4 | x43 | b_x3]
// ---------------------------------------------------------------------------
__global__ __launch_bounds__(256) void k5_out(
    const float* __restrict__ V, const float* __restrict__ G,
    const float* __restrict__ b128, float* __restrict__ out)
{
  const int idx = blockIdx.x*256 + threadIdx.x;
  const int flat = idx << 2;
  const int hw = flat & 1023;
  const int ch = (flat >> 10) & 511;
  const int b  = flat >> 19;
  const int blk = ch >> 7, o = ch & 127;
  const int gidx = (blk == 0) ? 2 : (blk == 1) ? 0 : (blk == 2) ? 1 : 3;
  const int src = (blk >= 2) ? 1 : 0;

  const float4 v = *(const float4*)&V[((size_t)((src*8 + b)*128 + o) << 10) + hw];
  const float4 g = *(const float4*)&G[(size_t)gidx*8192 + b*1024 + hw];
  const float bias = b128[o];
  float4 r;
  r.x = g.x*v.x + bias; r.y = g.y*v.y + bias;
  r.z = g.z*v.z + bias; r.w = g.w*v.w + bias;
  *(float4*)&out[flat] = r;
}

// ---------------------------------------------------------------------------
extern "C" void kernel_launch(void* const* d_in, const int* in_sizes, int n_in,
                              void* d_out, int out_size, void* d_ws, size_t ws_size,
                              hipStream_t stream)
{
  const float* x4   = (const float*)d_in[0];
  const float* x3   = (const float*)d_in[1];
  const float* wq   = (const float*)d_in[2];
  const float* bq   = (const float*)d_in[3];
  const float* wk   = (const float*)d_in[4];
  const float* bk   = (const float*)d_in[5];
  const float* wv   = (const float*)d_in[6];
  const float* bv   = (const float*)d_in[7];
  const float* w128 = (const float*)d_in[8];
  const float* b128 = (const float*)d_in[9];
  float* out = (float*)d_out;

  char* ws = (char*)d_ws;
  uchar_t*  Qf8 = (uchar_t*)ws;  ws += (size_t)512*8*1024;      // 4 MB
  uchar_t*  Kf8 = (uchar_t*)ws;  ws += (size_t)512*8*1024;      // 4 MB
  float*    V   = (float*)ws;    ws += (size_t)2*8*128*1024*4;  // 8 MB
  float*    Pm  = (float*)ws;    ws += (size_t)16*16384*4;      // 1 MB
  ushort_t* Wf  = (ushort_t*)ws; ws += (size_t)640*256*2;       // 320 KB
  float* bias_all = (float*)ws;  ws += 640*4;
  float*    G   = (float*)ws;                                   // 128 KB

  k1_weights <<<544,          256, 0, stream>>>(wq, bq, wk, bk, wv, bv, w128, Wf, bias_all);
  k2_features<<<dim3(256, 2), 256, 0, stream>>>(x4, x3, Wf, bias_all, Qf8, Kf8, V);
  k3_smax    <<<1024,         256, 0, stream>>>(Qf8, Kf8, Pm);
  k4_gates   <<<16,          1024, 0, stream>>>(Pm, G);
  k5_out     <<<4096,         256, 0, stream>>>(V, G, b128, out);
}